// Round 3
// baseline (2293.276 us; speedup 1.0000x reference)
//
#include <hip/hip_runtime.h>
#include <hip/hip_cooperative_groups.h>

namespace cg = cooperative_groups;

#define NN 8192
#define STEPS 64
#define DECAYF 0.9f
#define THRESHF 1.0f
#define K_MAX 384            // padded-ELL row capacity (mean nnz ~257, max ~320)

#define CBLOCKS 256          // one block per CU
#define CTHREADS 1024        // 16 waves
#define ROWS_PER_BLOCK (NN / CBLOCKS)            // 32
#define WAVES_PER_BLOCK (CTHREADS / 64)          // 16
#define ROWS_PER_WAVE (ROWS_PER_BLOCK / WAVES_PER_BLOCK)  // 2

// ---------------------------------------------------------------------------
// One-time W -> padded-ELL extraction, float4 loads (HBM-bound, ~268 MB read).
// Order of nonzeros within a row is comp-major (irrelevant: fp64 accumulation
// makes the step sum order-independent to ~2^-52 relative).
// ---------------------------------------------------------------------------
__global__ __launch_bounds__(256) void extract_ell(
        const float* __restrict__ W,
        float* __restrict__ evals,
        unsigned short* __restrict__ ecols,
        int* __restrict__ counts) {
    const int wave = threadIdx.x >> 6;
    const int lane = threadIdx.x & 63;
    const int row  = blockIdx.x * 4 + wave;
    const float4* wr4  = (const float4*)(W + (size_t)row * NN);
    float* ev          = evals + (size_t)row * K_MAX;
    unsigned short* ec = ecols + (size_t)row * K_MAX;

    const unsigned long long lmask = (1ull << lane) - 1ull;
    int base = 0;
    for (int c4 = lane; c4 < NN / 4; c4 += 64) {   // 32 iters, 1 KB/wave/iter
        float4 w = wr4[c4];
        const int col0 = c4 * 4;
        #pragma unroll
        for (int comp = 0; comp < 4; ++comp) {
            float val = (comp == 0) ? w.x : (comp == 1) ? w.y : (comp == 2) ? w.z : w.w;
            unsigned long long m = __ballot(val != 0.0f);
            if (val != 0.0f) {
                int idx = base + __popcll(m & lmask);
                if (idx < K_MAX) {                 // statistically unreachable guard
                    ev[idx] = val;
                    ec[idx] = (unsigned short)(col0 + comp);
                }
            }
            base += __popcll(m);
        }
    }
    if (lane == 0) counts[row] = (base < K_MAX) ? base : K_MAX;
}

// ---------------------------------------------------------------------------
// Persistent cooperative kernel: all 64 LIF steps, grid-sync between steps.
// v lives in registers (row ownership is fixed). f ping-pongs through global.
// ---------------------------------------------------------------------------
__global__ __launch_bounds__(CTHREADS) void coop_steps(
        const float* __restrict__ evals,
        const unsigned short* __restrict__ ecols,
        const int* __restrict__ counts,
        const float* __restrict__ f0,
        const float* __restrict__ v0,
        float* __restrict__ fA,
        float* __restrict__ fB,
        float* __restrict__ out) {
    cg::grid_group grid = cg::this_grid();
    __shared__ float fsh[NN];                      // 32 KB firing vector
    const int tid  = threadIdx.x;
    const int wave = tid >> 6;
    const int lane = tid & 63;
    const int r0 = blockIdx.x * ROWS_PER_BLOCK + wave * ROWS_PER_WAVE;
    const int r1 = r0 + 1;

    const int cnt0 = counts[r0];
    const int cnt1 = counts[r1];
    const float* ev0          = evals + (size_t)r0 * K_MAX;
    const float* ev1          = evals + (size_t)r1 * K_MAX;
    const unsigned short* ec0 = ecols + (size_t)r0 * K_MAX;
    const unsigned short* ec1 = ecols + (size_t)r1 * K_MAX;

    // membrane potentials in registers (only lane 0's copy is live)
    float vr0 = v0[r0];
    float vr1 = v0[r1];

    const float* fin = f0;
    for (int s = 0; s < STEPS; ++s) {
        // stage firing vector into LDS (2 float4 per thread)
        const float4* f4 = (const float4*)fin;
        float4* fsh4 = (float4*)fsh;
        #pragma unroll
        for (int k = tid; k < NN / 4; k += CTHREADS) fsh4[k] = f4[k];
        __syncthreads();

        float* fout = (s & 1) ? fB : fA;
        float* orow = out + (size_t)s * NN;

        // row 0
        {
            double acc = 0.0;
            for (int j = lane; j < cnt0; j += 64)
                acc += (double)ev0[j] * (double)fsh[ec0[j]];
            #pragma unroll
            for (int off = 32; off >= 1; off >>= 1)
                acc += __shfl_down(acc, off, 64);
            if (lane == 0) {
                float u  = (float)acc;
                float vv = __fadd_rn(__fmul_rn(DECAYF, vr0), u);
                float fire = (vv >= THRESHF) ? 1.0f : 0.0f;
                vr0 = (vv >= THRESHF) ? 0.0f : vv;
                fout[r0] = fire;
                orow[r0] = fire;
            }
        }
        // row 1
        {
            double acc = 0.0;
            for (int j = lane; j < cnt1; j += 64)
                acc += (double)ev1[j] * (double)fsh[ec1[j]];
            #pragma unroll
            for (int off = 32; off >= 1; off >>= 1)
                acc += __shfl_down(acc, off, 64);
            if (lane == 0) {
                float u  = (float)acc;
                float vv = __fadd_rn(__fmul_rn(DECAYF, vr1), u);
                float fire = (vv >= THRESHF) ? 1.0f : 0.0f;
                vr1 = (vv >= THRESHF) ? 0.0f : vv;
                fout[r1] = fire;
                orow[r1] = fire;
            }
        }

        grid.sync();   // f_{s+1} visible device-wide; also block-level barrier for fsh reuse
        fin = fout;
    }
}

extern "C" void kernel_launch(void* const* d_in, const int* in_sizes, int n_in,
                              void* d_out, int out_size, void* d_ws, size_t ws_size,
                              hipStream_t stream) {
    const float* W  = (const float*)d_in[0];
    const float* f0 = (const float*)d_in[1];
    const float* v0 = (const float*)d_in[2];
    float* out = (float*)d_out;

    // workspace layout: ELL vals | ELL cols | counts | f ping-pong
    float* evals          = (float*)d_ws;                                   // 8192*384*4 B
    unsigned short* ecols = (unsigned short*)(evals + (size_t)NN * K_MAX);  // 8192*384*2 B
    int* counts           = (int*)(ecols + (size_t)NN * K_MAX);
    float* fA             = (float*)(counts + NN);
    float* fB             = fA + NN;

    extract_ell<<<NN / 4, 256, 0, stream>>>(W, evals, ecols, counts);

    void* args[] = {
        (void*)&evals, (void*)&ecols, (void*)&counts,
        (void*)&f0, (void*)&v0, (void*)&fA, (void*)&fB, (void*)&out
    };
    hipLaunchCooperativeKernel((const void*)coop_steps,
                               dim3(CBLOCKS), dim3(CTHREADS),
                               args, 0, stream);
}

// Round 4
// 1159.808 us; speedup vs baseline: 1.9773x; 1.9773x over previous
//
#include <hip/hip_runtime.h>

#define NN 8192
#define STEPS 64
#define DECAYF 0.9f
#define THRESHF 1.0f
#define K_MAX 384            // padded-ELL row capacity (mean nnz ~257, max ~320)

#define CBLOCKS 256          // one block per CU (cooperative launch => co-resident)
#define CTHREADS 1024        // 16 waves
#define ROWS_PER_BLOCK (NN / CBLOCKS)                     // 32
#define ROWS_PER_WAVE  (ROWS_PER_BLOCK / (CTHREADS / 64)) // 2

// Agent-scope (device) accesses: compile to sc0+sc1 loads/stores that bypass
// L1/L2 and hit the Infinity Cache (the cross-XCD coherence point). No cache
// maintenance instructions => ELL data stays L2-resident across all steps.
__device__ __forceinline__ void agent_store_f32(float* p, float v) {
    __hip_atomic_store(p, v, __ATOMIC_RELAXED, __HIP_MEMORY_SCOPE_AGENT);
}
__device__ __forceinline__ unsigned long long agent_load_u64(const unsigned long long* p) {
    return __hip_atomic_load(p, __ATOMIC_RELAXED, __HIP_MEMORY_SCOPE_AGENT);
}

// ---------------------------------------------------------------------------
// One-time W -> padded-ELL extraction, float4 loads (HBM-bound, ~268 MB read).
// Also zero-inits the barrier counter (ws is poisoned 0xAA before every call).
// ---------------------------------------------------------------------------
__global__ __launch_bounds__(256) void extract_ell(
        const float* __restrict__ W,
        float* __restrict__ evals,
        unsigned short* __restrict__ ecols,
        int* __restrict__ counts,
        unsigned int* __restrict__ bar) {
    if (blockIdx.x == 0 && threadIdx.x == 0) *bar = 0;   // visible at next dispatch

    const int wave = threadIdx.x >> 6;
    const int lane = threadIdx.x & 63;
    const int row  = blockIdx.x * 4 + wave;
    const float4* wr4  = (const float4*)(W + (size_t)row * NN);
    float* ev          = evals + (size_t)row * K_MAX;
    unsigned short* ec = ecols + (size_t)row * K_MAX;

    const unsigned long long lmask = (1ull << lane) - 1ull;
    int base = 0;
    for (int c4 = lane; c4 < NN / 4; c4 += 64) {
        float4 w = wr4[c4];
        const int col0 = c4 * 4;
        #pragma unroll
        for (int comp = 0; comp < 4; ++comp) {
            float val = (comp == 0) ? w.x : (comp == 1) ? w.y : (comp == 2) ? w.z : w.w;
            unsigned long long m = __ballot(val != 0.0f);
            if (val != 0.0f) {
                int idx = base + __popcll(m & lmask);
                if (idx < K_MAX) {                 // statistically unreachable guard
                    ev[idx] = val;
                    ec[idx] = (unsigned short)(col0 + comp);
                }
            }
            base += __popcll(m);
        }
    }
    if (lane == 0) counts[row] = (base < K_MAX) ? base : K_MAX;
}

// ---------------------------------------------------------------------------
// Persistent kernel: 64 LIF steps with a hand-rolled fence-free grid barrier.
// ---------------------------------------------------------------------------
__global__ __launch_bounds__(CTHREADS) void coop_steps(
        const float* __restrict__ evals,
        const unsigned short* __restrict__ ecols,
        const int* __restrict__ counts,
        const float* __restrict__ f0,
        const float* __restrict__ v0,
        float* __restrict__ fA,
        float* __restrict__ fB,
        float* __restrict__ out,
        unsigned int* __restrict__ bar) {
    __shared__ float fsh[NN];                      // 32 KB firing vector
    const int tid  = threadIdx.x;
    const int wave = tid >> 6;
    const int lane = tid & 63;
    const int r0 = blockIdx.x * ROWS_PER_BLOCK + wave * ROWS_PER_WAVE;
    const int r1 = r0 + 1;

    const int cnt0 = counts[r0];
    const int cnt1 = counts[r1];
    const float* ev0          = evals + (size_t)r0 * K_MAX;
    const float* ev1          = evals + (size_t)r1 * K_MAX;
    const unsigned short* ec0 = ecols + (size_t)r0 * K_MAX;
    const unsigned short* ec1 = ecols + (size_t)r1 * K_MAX;

    float vr0 = v0[r0];        // membrane potentials live in registers
    float vr1 = v0[r1];        // (only lane 0's copy is meaningful)

    const float* fin = f0;
    for (int s = 0; s < STEPS; ++s) {
        // ---- stage firing vector into LDS via L2-bypassing 8-byte loads ----
        const unsigned long long* fin8 = (const unsigned long long*)fin;
        unsigned long long* fsh8 = (unsigned long long*)fsh;
        #pragma unroll
        for (int k = tid; k < NN / 2; k += CTHREADS)    // 4 per thread
            fsh8[k] = agent_load_u64(fin8 + k);
        __syncthreads();

        float* fout = (s & 1) ? fB : fA;
        float* orow = out + (size_t)s * NN;

        // ---- row 0 ----
        {
            double acc = 0.0;
            for (int j = lane; j < cnt0; j += 64)
                acc += (double)ev0[j] * (double)fsh[ec0[j]];
            #pragma unroll
            for (int off = 32; off >= 1; off >>= 1)
                acc += __shfl_down(acc, off, 64);
            if (lane == 0) {
                float u  = (float)acc;
                float vv = __fadd_rn(__fmul_rn(DECAYF, vr0), u);
                float fire = (vv >= THRESHF) ? 1.0f : 0.0f;
                vr0 = (vv >= THRESHF) ? 0.0f : vv;
                agent_store_f32(&fout[r0], fire);   // straight to L3 (coherent)
                orow[r0] = fire;                    // host-only: regular store
            }
        }
        // ---- row 1 ----
        {
            double acc = 0.0;
            for (int j = lane; j < cnt1; j += 64)
                acc += (double)ev1[j] * (double)fsh[ec1[j]];
            #pragma unroll
            for (int off = 32; off >= 1; off >>= 1)
                acc += __shfl_down(acc, off, 64);
            if (lane == 0) {
                float u  = (float)acc;
                float vv = __fadd_rn(__fmul_rn(DECAYF, vr1), u);
                float fire = (vv >= THRESHF) ? 1.0f : 0.0f;
                vr1 = (vv >= THRESHF) ? 0.0f : vv;
                agent_store_f32(&fout[r1], fire);
                orow[r1] = fire;
            }
        }

        // ---- fence-free grid barrier ----
        // Each wave drains its own sc1 stores to L3, block-barrier, then one
        // arrive + poll per block on a monotonic counter at L3.
        __builtin_amdgcn_s_waitcnt(0);
        __syncthreads();
        if (tid == 0) {
            __hip_atomic_fetch_add(bar, 1u, __ATOMIC_RELAXED, __HIP_MEMORY_SCOPE_AGENT);
            const unsigned int target = (unsigned int)(s + 1) * CBLOCKS;
            while (__hip_atomic_load(bar, __ATOMIC_RELAXED, __HIP_MEMORY_SCOPE_AGENT) < target)
                __builtin_amdgcn_s_sleep(1);
        }
        __syncthreads();

        fin = fout;
    }
}

extern "C" void kernel_launch(void* const* d_in, const int* in_sizes, int n_in,
                              void* d_out, int out_size, void* d_ws, size_t ws_size,
                              hipStream_t stream) {
    const float* W  = (const float*)d_in[0];
    const float* f0 = (const float*)d_in[1];
    const float* v0 = (const float*)d_in[2];
    float* out = (float*)d_out;

    // workspace layout: ELL vals | ELL cols | counts | f ping-pong | barrier
    float* evals          = (float*)d_ws;                                   // 8192*384*4 B
    unsigned short* ecols = (unsigned short*)(evals + (size_t)NN * K_MAX);  // 8192*384*2 B
    int* counts           = (int*)(ecols + (size_t)NN * K_MAX);
    float* fA             = (float*)(counts + NN);      // 8-byte aligned
    float* fB             = fA + NN;
    unsigned int* bar     = (unsigned int*)(fB + NN);

    extract_ell<<<NN / 4, 256, 0, stream>>>(W, evals, ecols, counts, bar);

    void* args[] = {
        (void*)&evals, (void*)&ecols, (void*)&counts,
        (void*)&f0, (void*)&v0, (void*)&fA, (void*)&fB, (void*)&out, (void*)&bar
    };
    hipLaunchCooperativeKernel((const void*)coop_steps,
                               dim3(CBLOCKS), dim3(CTHREADS),
                               args, 0, stream);
}

// Round 6
// 732.236 us; speedup vs baseline: 3.1319x; 1.5839x over previous
//
#include <hip/hip_runtime.h>

#define NN 8192
#define STEPS 64
#define DECAYF 0.9f
#define THRESHF 1.0f
#define K_MAX 384            // padded-ELL row capacity (mean nnz ~257, max ~320)

#define CBLOCKS 256          // one block per CU (cooperative launch => co-resident)
#define CTHREADS 1024        // 16 waves
#define NWAVES 16
#define ROWS_PER_BLOCK 32    // 2 rows per wave; one u32 firing word per block

typedef unsigned long long u64;
typedef unsigned int u32;
typedef unsigned short u16;

// Relaxed agent-scope accesses: sc0+sc1, bypass L1/L2, coherent at Infinity
// Cache. One aligned u64 store = atomic publish of (step_tag<<32 | fire_bits):
// barrier-arrive and data-exchange are the SAME operation. No fences anywhere.
//
// DOUBLE-BUFFERED by step parity (R5 post-mortem): input for step s lives in
// slot s&1 tagged s+1. Slot s&1 is only overwritten at step s+1's publish,
// which happens after polling slot (s+1)&1 for all tags s+2 — and a block
// publishes s+2 only after it finished reading slot s&1. Hence no slot is
// overwritten while any reader still needs it; '== want' polls terminate.
__device__ __forceinline__ void pub_store(u64* p, u64 v) {
    __hip_atomic_store(p, v, __ATOMIC_RELAXED, __HIP_MEMORY_SCOPE_AGENT);
}
__device__ __forceinline__ u64 pub_load(const u64* p) {
    return __hip_atomic_load(p, __ATOMIC_RELAXED, __HIP_MEMORY_SCOPE_AGENT);
}

__global__ __launch_bounds__(CTHREADS) void spiking_all(
        const float* __restrict__ W,
        const float* __restrict__ f0,
        const float* __restrict__ v0,
        float* __restrict__ out,
        u64* __restrict__ fdata) {     // [2][CBLOCKS]
    __shared__ float lds_vals[ROWS_PER_BLOCK * K_MAX];   // 48 KB
    __shared__ u16   lds_cols[ROWS_PER_BLOCK * K_MAX];   // 24 KB
    __shared__ int   lds_cnt[ROWS_PER_BLOCK];
    __shared__ u32   lds_fbits[CBLOCKS];                 // 1 KB firing bitmask
    __shared__ u32   lds_spike[NWAVES];

    const int tid  = threadIdx.x;
    const int wave = tid >> 6;
    const int lane = tid & 63;
    const int bid  = blockIdx.x;
    const u64 lmask = (1ull << lane) - 1ull;

    const int r0 = bid * ROWS_PER_BLOCK + wave * 2;  // this wave's two rows
    const int r1 = r0 + 1;

    // ---- Phase A: extract this block's 32 W rows (1 MB, contiguous) into
    //      LDS ELL. HBM-bound, W read exactly once. ----
    for (int rr = 0; rr < 2; ++rr) {
        const int lr  = wave * 2 + rr;
        const int row = bid * ROWS_PER_BLOCK + lr;
        const float4* wr4 = (const float4*)(W + (size_t)row * NN);
        float* ev = lds_vals + lr * K_MAX;
        u16*   ec = lds_cols + lr * K_MAX;
        int base = 0;
        for (int c4 = lane; c4 < NN / 4; c4 += 64) {
            float4 w = wr4[c4];
            const int col0 = c4 * 4;
            #pragma unroll
            for (int comp = 0; comp < 4; ++comp) {
                float val = (comp == 0) ? w.x : (comp == 1) ? w.y
                          : (comp == 2) ? w.z : w.w;
                u64 m = __ballot(val != 0.0f);
                if (val != 0.0f) {
                    int idx = base + __popcll(m & lmask);
                    if (idx < K_MAX) {               // statistically unreachable
                        ev[idx] = val;
                        ec[idx] = (u16)(col0 + comp);
                    }
                }
                base += __popcll(m);
            }
        }
        if (lane == 0) lds_cnt[lr] = (base < K_MAX) ? base : K_MAX;
    }

    // ---- Phase B: membrane state in registers; publish f0 bits into slot 0
    //      with tag 1 (step 0's input). ----
    float vr0 = v0[r0];
    float vr1 = v0[r1];
    if (wave == 0) {
        float f = (lane < ROWS_PER_BLOCK) ? f0[bid * ROWS_PER_BLOCK + lane] : 0.0f;
        u64 m = __ballot(f != 0.0f);                 // bits 0..31 = our rows
        if (lane == 0)
            pub_store(&fdata[bid], (1ull << 32) | (u32)(m & 0xffffffffull));
    }
    __syncthreads();

    // ---- Step loop: read slot s&1 (tag s+1), publish slot (s+1)&1 (tag s+2) ----
    for (int s = 0; s < STEPS; ++s) {
        const u32 want = (u32)(s + 1);
        const u64* slot_in = fdata + (size_t)(s & 1) * CBLOCKS;
        u64*       slot_out = fdata + (size_t)((s + 1) & 1) * CBLOCKS;

        // wave 0: poll all 256 words of the input slot; tag check and payload
        // come from the same atomic u64 load, so they are consistent.
        if (wave == 0) {
            u64 w0, w1, w2, w3;
            for (;;) {
                w0 = pub_load(&slot_in[lane]);
                w1 = pub_load(&slot_in[lane + 64]);
                w2 = pub_load(&slot_in[lane + 128]);
                w3 = pub_load(&slot_in[lane + 192]);
                int ok = ((u32)(w0 >> 32) == want) & ((u32)(w1 >> 32) == want)
                       & ((u32)(w2 >> 32) == want) & ((u32)(w3 >> 32) == want);
                if (__all(ok)) break;
                __builtin_amdgcn_s_sleep(1);
            }
            lds_fbits[lane]       = (u32)w0;
            lds_fbits[lane + 64]  = (u32)w1;
            lds_fbits[lane + 128] = (u32)w2;
            lds_fbits[lane + 192] = (u32)w3;
        }
        __syncthreads();

        float* orow = out + (size_t)s * NN;
        u32 myspike = 0;

        // row 0: bit-test gather, conditional fp64 add (f is exactly 0/1)
        {
            const int lr  = wave * 2;
            const int cnt = lds_cnt[lr];
            const float* ev = lds_vals + lr * K_MAX;
            const u16*   ec = lds_cols + lr * K_MAX;
            double acc = 0.0;
            for (int j = lane; j < cnt; j += 64) {
                u16 c = ec[j];
                if ((lds_fbits[c >> 5] >> (c & 31)) & 1u)
                    acc += (double)ev[j];
            }
            #pragma unroll
            for (int off = 32; off >= 1; off >>= 1)
                acc += __shfl_down(acc, off, 64);
            if (lane == 0) {
                float u  = (float)acc;
                float vv = __fadd_rn(__fmul_rn(DECAYF, vr0), u);
                int fire = (vv >= THRESHF);
                vr0 = fire ? 0.0f : vv;
                orow[r0] = fire ? 1.0f : 0.0f;
                myspike = (u32)fire;
            }
        }
        // row 1
        {
            const int lr  = wave * 2 + 1;
            const int cnt = lds_cnt[lr];
            const float* ev = lds_vals + lr * K_MAX;
            const u16*   ec = lds_cols + lr * K_MAX;
            double acc = 0.0;
            for (int j = lane; j < cnt; j += 64) {
                u16 c = ec[j];
                if ((lds_fbits[c >> 5] >> (c & 31)) & 1u)
                    acc += (double)ev[j];
            }
            #pragma unroll
            for (int off = 32; off >= 1; off >>= 1)
                acc += __shfl_down(acc, off, 64);
            if (lane == 0) {
                float u  = (float)acc;
                float vv = __fadd_rn(__fmul_rn(DECAYF, vr1), u);
                int fire = (vv >= THRESHF);
                vr1 = fire ? 0.0f : vv;
                orow[r1] = fire ? 1.0f : 0.0f;
                myspike |= (u32)fire << 1;
                lds_spike[wave] = myspike;       // 2 bits at position 2*wave
            }
        }
        __syncthreads();

        // wave 0: assemble the block's 32 fire bits, publish into the OTHER
        // slot with tag s+2. (lds_spike reads finish before wave 0 reaches the
        // next step's post-poll __syncthreads, so no extra barrier needed.)
        if (wave == 0) {
            u32 bits = (lane < NWAVES) ? (lds_spike[lane] << (2 * lane)) : 0u;
            #pragma unroll
            for (int off = 8; off >= 1; off >>= 1)
                bits |= __shfl_down(bits, off, 64);
            if (lane == 0)
                pub_store(&slot_out[bid], ((u64)(u32)(s + 2) << 32) | bits);
        }
    }
}

extern "C" void kernel_launch(void* const* d_in, const int* in_sizes, int n_in,
                              void* d_out, int out_size, void* d_ws, size_t ws_size,
                              hipStream_t stream) {
    const float* W  = (const float*)d_in[0];
    const float* f0 = (const float*)d_in[1];
    const float* v0 = (const float*)d_in[2];
    float* out = (float*)d_out;

    u64* fdata = (u64*)d_ws;    // [2][256] u64 = 4 KB; re-seeded in-kernel each call

    void* args[] = { (void*)&W, (void*)&f0, (void*)&v0, (void*)&out, (void*)&fdata };
    hipLaunchCooperativeKernel((const void*)spiking_all,
                               dim3(CBLOCKS), dim3(CTHREADS),
                               args, 0, stream);
}

// Round 7
// 691.700 us; speedup vs baseline: 3.3154x; 1.0586x over previous
//
#include <hip/hip_runtime.h>

#define NN 8192
#define STEPS 64
#define DECAYF 0.9f
#define THRESHF 1.0f
#define K_MAX 384            // padded-ELL row capacity (mean nnz ~257, max ~320)

#define CBLOCKS 256          // one block per CU; regular launch (1024 thr, 75 KB LDS,
                             // ~20 VGPR => every CU takes its block immediately)
#define CTHREADS 1024        // 16 waves
#define NWAVES 16
#define ROWS_PER_BLOCK 32    // 2 rows per wave; one u32 firing word per block

typedef unsigned long long u64;
typedef unsigned int u32;
typedef unsigned short u16;

// Relaxed agent-scope accesses: sc0+sc1, bypass L1/L2, coherent at Infinity
// Cache. One aligned u64 = (step_tag<<32 | fire_bits): publish and barrier-
// arrive are the same store; tag+payload are consistent by construction.
//
// PUSH-MODEL MAILBOXES (R6 post-mortem): mb[2][dest][src]. Writer scatters its
// word to all 256 dest rows; reader polls ONLY its own contiguous 2 KB row.
// No two blocks poll the same cache lines => no L3 hot-spot. Parity double-
// buffering: slot s&1 carries step-s input (tag s+1); it is next overwritten
// at tag s+3, which a writer sends only after seeing all tags s+2 — and a
// block sends s+2 only after it finished reading slot s&1. No overwrite race.
__device__ __forceinline__ void pub_store(u64* p, u64 v) {
    __hip_atomic_store(p, v, __ATOMIC_RELAXED, __HIP_MEMORY_SCOPE_AGENT);
}
__device__ __forceinline__ u64 pub_load(const u64* p) {
    return __hip_atomic_load(p, __ATOMIC_RELAXED, __HIP_MEMORY_SCOPE_AGENT);
}

__global__ __launch_bounds__(CTHREADS) void spiking_all(
        const float* __restrict__ W,
        const float* __restrict__ f0,
        const float* __restrict__ v0,
        float* __restrict__ out,
        u64* __restrict__ mb) {        // [2][CBLOCKS dest][CBLOCKS src]
    __shared__ float lds_vals[ROWS_PER_BLOCK * K_MAX];   // 48 KB
    __shared__ u16   lds_cols[ROWS_PER_BLOCK * K_MAX];   // 24 KB
    __shared__ int   lds_cnt[ROWS_PER_BLOCK];
    __shared__ u32   lds_fbits[CBLOCKS];                 // 1 KB firing bitmask
    __shared__ u32   lds_spike[NWAVES];

    const int tid  = threadIdx.x;
    const int wave = tid >> 6;
    const int lane = tid & 63;
    const int bid  = blockIdx.x;
    const u64 lmask = (1ull << lane) - 1ull;

    const int r0 = bid * ROWS_PER_BLOCK + wave * 2;  // this wave's two rows
    const int r1 = r0 + 1;

    // ---- Phase A: extract this block's 32 W rows (1 MB, contiguous) into
    //      LDS ELL. HBM-bound, W read exactly once. ----
    for (int rr = 0; rr < 2; ++rr) {
        const int lr  = wave * 2 + rr;
        const int row = bid * ROWS_PER_BLOCK + lr;
        const float4* wr4 = (const float4*)(W + (size_t)row * NN);
        float* ev = lds_vals + lr * K_MAX;
        u16*   ec = lds_cols + lr * K_MAX;
        int base = 0;
        for (int c4 = lane; c4 < NN / 4; c4 += 64) {
            float4 w = wr4[c4];
            const int col0 = c4 * 4;
            #pragma unroll
            for (int comp = 0; comp < 4; ++comp) {
                float val = (comp == 0) ? w.x : (comp == 1) ? w.y
                          : (comp == 2) ? w.z : w.w;
                u64 m = __ballot(val != 0.0f);
                if (val != 0.0f) {
                    int idx = base + __popcll(m & lmask);
                    if (idx < K_MAX) {               // statistically unreachable
                        ev[idx] = val;
                        ec[idx] = (u16)(col0 + comp);
                    }
                }
                base += __popcll(m);
            }
        }
        if (lane == 0) lds_cnt[lr] = (base < K_MAX) ? base : K_MAX;
    }

    // ---- Phase B: membrane state in registers; scatter f0 word (tag 1) into
    //      slot 0 of every destination row. ----
    float vr0 = v0[r0];
    float vr1 = v0[r1];
    if (wave == 0) {
        float f = (lane < ROWS_PER_BLOCK) ? f0[bid * ROWS_PER_BLOCK + lane] : 0.0f;
        u64 m = __ballot(f != 0.0f);                 // bits 0..31 = our rows
        u32 bits = (u32)(m & 0xffffffffull);
        u64 word = (1ull << 32) | bits;
        u64* basep = mb + bid;                       // slot 0
        #pragma unroll
        for (int k = 0; k < 4; ++k)
            pub_store(basep + ((size_t)(lane + 64 * k) << 8), word);
    }
    __syncthreads();

    // ---- Step loop: read own row of slot s&1 (tag s+1); scatter tag s+2
    //      into slot (s+1)&1 of all rows. ----
    for (int s = 0; s < STEPS; ++s) {
        const u32 want = (u32)(s + 1);
        const u64* myrow = mb + (size_t)(s & 1) * (CBLOCKS * CBLOCKS)
                              + (size_t)bid * CBLOCKS;

        // wave 0: poll own private 2 KB row (coalesced; no line sharing).
        if (wave == 0) {
            u64 w0, w1, w2, w3;
            for (;;) {
                w0 = pub_load(&myrow[lane]);
                w1 = pub_load(&myrow[lane + 64]);
                w2 = pub_load(&myrow[lane + 128]);
                w3 = pub_load(&myrow[lane + 192]);
                int ok = ((u32)(w0 >> 32) == want) & ((u32)(w1 >> 32) == want)
                       & ((u32)(w2 >> 32) == want) & ((u32)(w3 >> 32) == want);
                if (__all(ok)) break;
                __builtin_amdgcn_s_sleep(8);
            }
            lds_fbits[lane]       = (u32)w0;
            lds_fbits[lane + 64]  = (u32)w1;
            lds_fbits[lane + 128] = (u32)w2;
            lds_fbits[lane + 192] = (u32)w3;
        }
        __syncthreads();

        float* orow = out + (size_t)s * NN;
        u32 myspike = 0;

        // row 0: bit-test gather, conditional fp64 add (f is exactly 0/1)
        {
            const int lr  = wave * 2;
            const int cnt = lds_cnt[lr];
            const float* ev = lds_vals + lr * K_MAX;
            const u16*   ec = lds_cols + lr * K_MAX;
            double acc = 0.0;
            for (int j = lane; j < cnt; j += 64) {
                u16 c = ec[j];
                if ((lds_fbits[c >> 5] >> (c & 31)) & 1u)
                    acc += (double)ev[j];
            }
            #pragma unroll
            for (int off = 32; off >= 1; off >>= 1)
                acc += __shfl_down(acc, off, 64);
            if (lane == 0) {
                float u  = (float)acc;
                float vv = __fadd_rn(__fmul_rn(DECAYF, vr0), u);
                int fire = (vv >= THRESHF);
                vr0 = fire ? 0.0f : vv;
                orow[r0] = fire ? 1.0f : 0.0f;
                myspike = (u32)fire;
            }
        }
        // row 1
        {
            const int lr  = wave * 2 + 1;
            const int cnt = lds_cnt[lr];
            const float* ev = lds_vals + lr * K_MAX;
            const u16*   ec = lds_cols + lr * K_MAX;
            double acc = 0.0;
            for (int j = lane; j < cnt; j += 64) {
                u16 c = ec[j];
                if ((lds_fbits[c >> 5] >> (c & 31)) & 1u)
                    acc += (double)ev[j];
            }
            #pragma unroll
            for (int off = 32; off >= 1; off >>= 1)
                acc += __shfl_down(acc, off, 64);
            if (lane == 0) {
                float u  = (float)acc;
                float vv = __fadd_rn(__fmul_rn(DECAYF, vr1), u);
                int fire = (vv >= THRESHF);
                vr1 = fire ? 0.0f : vv;
                orow[r1] = fire ? 1.0f : 0.0f;
                myspike |= (u32)fire << 1;
                lds_spike[wave] = myspike;       // 2 bits at position 2*wave
            }
        }
        __syncthreads();

        // wave 0: assemble the block's 32 fire bits, scatter (tag s+2) into
        // the other slot of all 256 destination rows. (lds_spike reads finish
        // before wave 0 joins the next step's post-poll barrier.)
        if (wave == 0) {
            u32 bits = (lane < NWAVES) ? (lds_spike[lane] << (2 * lane)) : 0u;
            #pragma unroll
            for (int off = 8; off >= 1; off >>= 1)
                bits |= __shfl_down(bits, off, 64);
            bits = __shfl(bits, 0, 64);
            u64 word = ((u64)(u32)(s + 2) << 32) | bits;
            u64* basep = mb + (size_t)((s + 1) & 1) * (CBLOCKS * CBLOCKS) + bid;
            #pragma unroll
            for (int k = 0; k < 4; ++k)
                pub_store(basep + ((size_t)(lane + 64 * k) << 8), word);
        }
    }
}

extern "C" void kernel_launch(void* const* d_in, const int* in_sizes, int n_in,
                              void* d_out, int out_size, void* d_ws, size_t ws_size,
                              hipStream_t stream) {
    const float* W  = (const float*)d_in[0];
    const float* f0 = (const float*)d_in[1];
    const float* v0 = (const float*)d_in[2];
    float* out = (float*)d_out;

    u64* mb = (u64*)d_ws;   // [2][256][256] u64 = 1 MB; 0xAA poison != any tag

    spiking_all<<<dim3(CBLOCKS), dim3(CTHREADS), 0, stream>>>(W, f0, v0, out, mb);
}